// Round 1
// baseline (60.217 us; speedup 1.0000x reference)
//
#include <hip/hip_runtime.h>
#include <math.h>

#define BATCH 4
#define CH 128
#define NOSC 128
#define TK 128
#define NAUD 32768

// ---------------- Stage 1: knots + phase-base scan ----------------
// One block per (b, osc); 128 threads = one per time-knot k.
__global__ __launch_bounds__(128) void osc1_kernel(
    const float* __restrict__ x, const float* __restrict__ W,
    const float* __restrict__ bvec, const float* __restrict__ baselines,
    float* __restrict__ fK, float* __restrict__ aK, double* __restrict__ C)
{
    const int blk = blockIdx.x;
    const int b = blk >> 7;
    const int o = blk & 127;
    const int k = threadIdx.x;

    __shared__ float Wr[CH];
    __shared__ float Wi[CH];
    Wr[k] = W[(2*o)*CH + k];
    Wi[k] = W[(2*o+1)*CH + k];
    __syncthreads();

    const float* xb = x + b*CH*TK + k;
    float re = bvec[2*o];
    float im = bvec[2*o+1];
    #pragma unroll 8
    for (int c = 0; c < CH; ++c) {
        float xv = xb[c*TK];           // coalesced across threads (t-contig)
        re = fmaf(xv, Wr[c], re);
        im = fmaf(xv, Wi[c], im);
    }
    re = fmaf(re, 0.01f, baselines[2*o]);
    im = fmaf(im, 0.01f, baselines[2*o+1]);

    const float BASEF  = (float)(40.0/11025.0);
    const float RANGEF = (float)(8960.0/11025.0);
    float amp = fmaf(fmaf(re, re, im*im), RANGEF, BASEF);   // BASE + (r^2+i^2)*RANGE
    double th = atan2((double)im, (double)re) * (1.0/3.14159265358979323846);
    float fr = (float)(th*th);                              // (atan2/pi)^2

    const int idx = (b*NOSC + o)*TK + k;
    fK[idx] = fr;
    aK[idx] = amp;

    // Segment-sum scan (f64). e[0] = head (128 clamped samples of f0),
    // e[m] = 128*(f_{m-1}+f_m) for m>=1 (exact closed form of the 256-sample
    // linear-interp segment sum, since sum_j (2j+1)/512 = 128).
    __shared__ float  fsh[TK];
    __shared__ double e[TK];
    fsh[k] = fr;
    __syncthreads();
    double ev = (k == 0) ? 128.0*(double)fsh[0]
                         : 128.0*((double)fsh[k-1] + (double)fsh[k]);
    e[k] = ev;
    __syncthreads();
    #pragma unroll
    for (int off = 1; off < TK; off <<= 1) {
        double add = (k >= off) ? e[k-off] : 0.0;
        __syncthreads();
        e[k] += add;
        __syncthreads();
    }
    // C[k] (k<=126): freq-sum before segment k starts; C[127]: before tail region.
    C[idx] = e[k];
}

// ---------------- Stage 2: synthesize + reduce over oscillators ----------------
// One block per (b, 256-sample tile); each thread owns one output sample.
__global__ __launch_bounds__(256) void osc2_kernel(
    const float* __restrict__ fK, const float* __restrict__ aK,
    const double* __restrict__ C, float* __restrict__ out)
{
    const int blk = blockIdx.x;
    const int b = blk >> 7;
    const int t = (blk & 127)*256 + threadIdx.x;

    const double PI     = 3.14159265358979323846;
    const double TWOPI  = 6.2831853071795864769;
    const double INV2PI = 0.15915494309189533577;

    float acc = 0.0f;
    const float*  fB = fK + b*NOSC*TK;
    const float*  aB = aK + b*NOSC*TK;
    const double* cB = C  + b*NOSC*TK;

    if (t < 128) {                       // head: clamped to knot 0
        const double tp1 = (double)(t + 1);
        for (int o = 0; o < NOSC; ++o) {
            const int base = o*TK;
            double ph = tp1 * (double)fB[base] * PI;
            double red = fma(-rint(ph * INV2PI), TWOPI, ph);
            acc = fmaf(aB[base], sinf((float)red), acc);
        }
    } else if (t >= NAUD - 128) {        // tail: clamped to knot 127
        const double jp1 = (double)(t - (NAUD - 128) + 1);
        for (int o = 0; o < NOSC; ++o) {
            const int base = o*TK;
            double ph = (cB[base+127] + jp1*(double)fB[base+127]) * PI;
            double red = fma(-rint(ph * INV2PI), TWOPI, ph);
            acc = fmaf(aB[base+127], sinf((float)red), acc);
        }
    } else {                             // interior segment k, sample j
        const int k = (t - 128) >> 8;
        const int j = (t - 128) & 255;
        const double jp1  = (double)(j + 1);
        const double jsq  = jp1 * jp1 * (1.0/512.0);
        const float  w    = (float)(2*j + 1) * (1.0f/512.0f);
        for (int o = 0; o < NOSC; ++o) {
            const int base = o*TK + k;
            float f0 = fB[base], f1 = fB[base+1];
            double ph = (cB[base] + jp1*(double)f0 + (double)(f1 - f0)*jsq) * PI;
            float a0 = aB[base];
            float amp = fmaf(aB[base+1] - a0, w, a0);
            double red = fma(-rint(ph * INV2PI), TWOPI, ph);
            acc = fmaf(amp, sinf((float)red), acc);
        }
    }
    out[b*NAUD + t] = acc;
}

extern "C" void kernel_launch(void* const* d_in, const int* in_sizes, int n_in,
                              void* d_out, int out_size, void* d_ws, size_t ws_size,
                              hipStream_t stream)
{
    const float* x         = (const float*)d_in[0];
    const float* W         = (const float*)d_in[1];
    const float* bvec      = (const float*)d_in[2];
    const float* baselines = (const float*)d_in[3];
    float* out = (float*)d_out;

    char* ws = (char*)d_ws;
    float*  fK = (float*)(ws);             // 4*128*128*4 = 256 KiB
    float*  aK = (float*)(ws + 262144);    // 256 KiB
    double* C  = (double*)(ws + 524288);   // 512 KiB

    osc1_kernel<<<BATCH*NOSC, 128, 0, stream>>>(x, W, bvec, baselines, fK, aK, C);
    osc2_kernel<<<BATCH*(NAUD/256), 256, 0, stream>>>(fK, aK, C, out);
}

// Round 2
// 27.178 us; speedup vs baseline: 2.2157x; 2.2157x over previous
//
#include <hip/hip_runtime.h>
#include <math.h>

#define BATCH 4
#define CH 128
#define NOSC 128
#define TK 128
#define NAUD 32768
#define NVS 129          // virtual segments: 0=head, 1..127=interior k=vs-1, 128=tail
#define OSPLIT 8
#define OCHUNK (NOSC/OSPLIT)   // 16

// seg tuple layout (8 floats, 32B): {f0h, dfh, cRev, a0, da, pad, pad, pad}
//   rev(t) = cRev + jp1*f0h + dfh*jsq ;  amp(t) = a0 + da*w ;  osc = amp*sin(2*pi*rev)

// ---------------- Stage 1: dots + f64 phase scan -> per-segment tuples ----------------
__global__ __launch_bounds__(128) void osc1_kernel(
    const float* __restrict__ x, const float* __restrict__ W,
    const float* __restrict__ bvec, const float* __restrict__ baselines,
    float* __restrict__ seg)
{
    const int blk = blockIdx.x;
    const int b = blk >> 7, o = blk & 127, k = threadIdx.x;

    __shared__ float Wr[CH], Wi[CH];
    Wr[k] = W[(2*o)*CH + k];
    Wi[k] = W[(2*o+1)*CH + k];
    __syncthreads();

    const float* xb = x + b*CH*TK + k;
    float re = bvec[2*o], im = bvec[2*o+1];
    #pragma unroll 8
    for (int c = 0; c < CH; ++c) {
        float xv = xb[c*TK];              // coalesced (t-contiguous)
        re = fmaf(xv, Wr[c], re);
        im = fmaf(xv, Wi[c], im);
    }
    re = fmaf(re, 0.01f, baselines[2*o]);
    im = fmaf(im, 0.01f, baselines[2*o+1]);

    const float BASEF  = 40.0f/11025.0f;
    const float RANGEF = 8960.0f/11025.0f;
    float amp = fmaf(fmaf(re, re, im*im), RANGEF, BASEF);
    double th = atan2((double)im, (double)re) * (1.0/3.14159265358979323846);
    float fr = (float)(th*th);

    // inclusive scan of segment freq-sums (f64, exact closed form per segment)
    __shared__ float  fsh[TK], ash[TK];
    __shared__ double e[TK];
    fsh[k] = fr; ash[k] = amp;
    __syncthreads();
    double ev = (k == 0) ? 128.0*(double)fsh[0]
                         : 128.0*((double)fsh[k-1] + (double)fsh[k]);
    e[k] = ev;
    __syncthreads();
    #pragma unroll
    for (int off = 1; off < TK; off <<= 1) {
        double add = (k >= off) ? e[k-off] : 0.0;
        __syncthreads();
        e[k] += add;
        __syncthreads();
    }
    double xrev = e[k] * 0.5;                 // phase base in revolutions
    float cRev = (float)(xrev - floor(xrev)); // mod 1 rev, done in f64 once

    float* base = seg + ((size_t)(b*NVS)*NOSC + o)*8;

    // interior vs = k+1 (k<=126); tail vs=128 from k==127
    {
        const int vs = k + 1;
        float f0h = 0.5f*fr;
        float dfh = (k <= 126) ? 0.5f*(fsh[k+1] - fr) : 0.0f;
        float a0  = amp;
        float da  = (k <= 126) ? (ash[k+1] - amp) : 0.0f;
        float* p = base + (size_t)vs*NOSC*8;
        *(float4*)p = make_float4(f0h, dfh, cRev, a0);
        p[4] = da;
    }
    if (k == 0) {   // head vs=0: clamped to knot 0, phase base 0
        float* p = base;
        *(float4*)p = make_float4(0.5f*fr, 0.0f, 0.0f, amp);
        p[4] = 0.0f;
    }
}

// ---------------- Stage 2: synthesize, atomically reduce over osc chunks ----------------
__global__ __launch_bounds__(256) void osc2_kernel(
    const float* __restrict__ seg, float* __restrict__ out)
{
    const int blk   = blockIdx.x;
    const int b     = blk >> 10;
    const int tile  = (blk >> 3) & 127;
    const int chunk = blk & 7;
    const int t = tile*256 + threadIdx.x;
    const int r = t & 127, h = t >> 7;

    int vs;
    if (h == 0)        vs = 0;
    else if (h == 255) vs = 128;
    else               vs = ((h - 1) >> 1) + 1;
    const int jint = r + 1 + ((h != 0 && h != 255 && !(h & 1)) ? 128 : 0);
    const float jp1 = (float)jint;
    const float jsq = jp1*jp1*(1.0f/512.0f);
    const float w   = (2.0f*jp1 - 1.0f)*(1.0f/512.0f);

    const float* p = seg + ((size_t)(b*NVS + vs)*NOSC + chunk*OCHUNK)*8;
    float acc = 0.0f;
    #pragma unroll
    for (int i = 0; i < OCHUNK; ++i) {
        float4 v = *(const float4*)(p + i*8);   // {f0h, dfh, cRev, a0}
        float da = p[i*8 + 4];
        float rev = fmaf(v.y, jsq, fmaf(jp1, v.x, v.z));
        rev = rev - floorf(rev);                // [0,1)
        float s;
        asm("v_sin_f32 %0, %1" : "=v"(s) : "v"(rev));  // sin(2*pi*rev)
        acc = fmaf(fmaf(da, w, v.w), s, acc);
    }
    atomicAdd(&out[b*NAUD + t], acc);
}

extern "C" void kernel_launch(void* const* d_in, const int* in_sizes, int n_in,
                              void* d_out, int out_size, void* d_ws, size_t ws_size,
                              hipStream_t stream)
{
    const float* x         = (const float*)d_in[0];
    const float* W         = (const float*)d_in[1];
    const float* bvec      = (const float*)d_in[2];
    const float* baselines = (const float*)d_in[3];
    float* out = (float*)d_out;

    float* seg = (float*)d_ws;   // 4*129*128*8*4B = 2.11 MiB

    hipMemsetAsync(out, 0, (size_t)out_size*sizeof(float), stream);
    osc1_kernel<<<BATCH*NOSC, 128, 0, stream>>>(x, W, bvec, baselines, seg);
    osc2_kernel<<<BATCH*128*OSPLIT, 256, 0, stream>>>(seg, out);
}

// Round 3
// 22.131 us; speedup vs baseline: 2.7209x; 1.2280x over previous
//
#include <hip/hip_runtime.h>
#include <math.h>

#define BATCH 4
#define CH 128
#define NOSC 128
#define TK 128
#define NAUD 32768
#define NVS 129          // virtual segments: 0=head, 1..127=interior k=vs-1, 128=tail

// seg tuple layout (8 floats, 32B): {f0h, dfh, cRev, a0, da, pad, pad, pad}
//   rev(t) = cRev + jp1*f0h + dfh*jsq ;  amp(t) = a0 + da*w ;  osc = amp*sin(2*pi*rev)

// ---------------- Stage 1: dots + phase scan -> per-segment tuples ----------------
// One block per (b,o); 256 threads = 128 knots x 2 channel-halves.
__global__ __launch_bounds__(256) void osc1_kernel(
    const float* __restrict__ x, const float* __restrict__ W,
    const float* __restrict__ bvec, const float* __restrict__ baselines,
    float* __restrict__ seg)
{
    const int blk = blockIdx.x;
    const int b = blk >> 7, o = blk & 127;
    const int tid = threadIdx.x;
    const int k = tid & 127, half = tid >> 7;

    __shared__ float Wr[CH], Wi[CH];
    if (tid < CH) {
        Wr[tid] = W[(2*o)*CH + tid];
        Wi[tid] = W[(2*o+1)*CH + tid];
    }
    __syncthreads();

    // partial dot over 64 channels (both re and im)
    const float* xb = x + b*CH*TK + k;
    float re = 0.0f, im = 0.0f;
    const int c0 = half*64;
    #pragma unroll 8
    for (int c = c0; c < c0 + 64; ++c) {
        float xv = xb[c*TK];              // coalesced across lanes (t-contiguous)
        re = fmaf(xv, Wr[c], re);
        im = fmaf(xv, Wi[c], im);
    }
    __shared__ float sRe[256], sIm[256];
    sRe[tid] = re; sIm[tid] = im;
    __syncthreads();

    __shared__ float fsh[TK], ash[TK];
    __shared__ double wtot;
    if (tid < 128) {
        float rr = sRe[tid] + sRe[tid+128] + bvec[2*o];
        float ii = sIm[tid] + sIm[tid+128] + bvec[2*o+1];
        rr = fmaf(rr, 0.01f, baselines[2*o]);
        ii = fmaf(ii, 0.01f, baselines[2*o+1]);
        const float BASEF  = 40.0f/11025.0f;
        const float RANGEF = 8960.0f/11025.0f;
        float amp = fmaf(fmaf(rr, rr, ii*ii), RANGEF, BASEF);
        float th  = atan2f(ii, rr) * (1.0f/3.14159265358979323846f);
        float fr  = th*th;
        fsh[k] = fr; ash[k] = amp;
    }
    __syncthreads();
    if (tid < 128) {
        const float fr = fsh[k], amp = ash[k];
        // segment freq-sum scan (f64), closed form per 256-sample segment
        double ev = (k == 0) ? 128.0*(double)fr
                             : 128.0*((double)fsh[k-1] + (double)fr);
        const int lane = tid & 63;
        #pragma unroll
        for (int d = 1; d < 64; d <<= 1) {
            double up = __shfl_up(ev, d);
            if (lane >= d) ev += up;
        }
        if (tid == 63) wtot = ev;
        __syncthreads();
        if (tid >= 64) ev += wtot;

        double xrev = ev * 0.5;                    // phase base in revolutions
        float cRev = (float)(xrev - floor(xrev)); // mod 1 rev

        float* base = seg + ((size_t)(b*NVS)*NOSC + o)*8;
        // interior vs = k+1 (k<=126); tail vs=128 from k==127
        {
            const int vs = k + 1;
            float f0h = 0.5f*fr;
            float dfh = (k <= 126) ? 0.5f*(fsh[k+1] - fr) : 0.0f;
            float da  = (k <= 126) ? (ash[k+1] - amp) : 0.0f;
            float* p = base + (size_t)vs*NOSC*8;
            *(float4*)p = make_float4(f0h, dfh, cRev, amp);
            p[4] = da;
        }
        if (k == 0) {   // head vs=0: clamped to knot 0, phase base 0
            float* p = base;
            *(float4*)p = make_float4(0.5f*fr, 0.0f, 0.0f, amp);
            p[4] = 0.0f;
        }
    } else {
        __syncthreads();   // match the scan's barrier
    }
}

// ---------------- Stage 2: synthesize + in-block reduce over oscillators ----------------
// One block per (b, 64-sample tile); 256 thr = 64 samples x 4 osc-groups of 32.
__global__ __launch_bounds__(256) void osc2_kernel(
    const float* __restrict__ seg, float* __restrict__ out)
{
    const int blk  = blockIdx.x;
    const int b    = blk >> 9;
    const int tile = blk & 511;
    const int s    = threadIdx.x & 63;
    const int g    = threadIdx.x >> 6;

    const int t = tile*64 + s;
    const int r = t & 127, h = t >> 7;   // h uniform per block

    int vs;
    if (h == 0)        vs = 0;
    else if (h == 255) vs = 128;
    else               vs = ((h - 1) >> 1) + 1;
    const int jint = r + 1 + ((h != 0 && h != 255 && !(h & 1)) ? 128 : 0);
    const float jp1 = (float)jint;
    const float jsq = jp1*jp1*(1.0f/512.0f);
    const float w   = (2.0f*jp1 - 1.0f)*(1.0f/512.0f);

    const float* p = seg + ((size_t)(b*NVS + vs)*NOSC + g*32)*8;
    float acc = 0.0f;
    #pragma unroll
    for (int i = 0; i < 32; ++i) {
        float4 v = *(const float4*)(p + i*8);   // broadcast across the 64 sample-lanes' wave? (same addr per wave) -> L1 hit
        float da = p[i*8 + 4];
        float rev = fmaf(v.y, jsq, fmaf(jp1, v.x, v.z));
        rev = rev - floorf(rev);                // [0,1)
        float sn;
        asm("v_sin_f32 %0, %1" : "=v"(sn) : "v"(rev));  // sin(2*pi*rev)
        acc = fmaf(fmaf(da, w, v.w), sn, acc);
    }

    __shared__ float red[256];
    red[threadIdx.x] = acc;
    __syncthreads();
    if (threadIdx.x < 64) {
        float v = red[threadIdx.x] + red[threadIdx.x + 64]
                + red[threadIdx.x + 128] + red[threadIdx.x + 192];
        out[b*NAUD + t] = v;
    }
}

extern "C" void kernel_launch(void* const* d_in, const int* in_sizes, int n_in,
                              void* d_out, int out_size, void* d_ws, size_t ws_size,
                              hipStream_t stream)
{
    const float* x         = (const float*)d_in[0];
    const float* W         = (const float*)d_in[1];
    const float* bvec      = (const float*)d_in[2];
    const float* baselines = (const float*)d_in[3];
    float* out = (float*)d_out;

    float* seg = (float*)d_ws;   // 4*129*128*8*4B = 2.11 MiB

    osc1_kernel<<<BATCH*NOSC, 256, 0, stream>>>(x, W, bvec, baselines, seg);
    osc2_kernel<<<BATCH*512, 256, 0, stream>>>(seg, out);
}

// Round 4
// 17.044 us; speedup vs baseline: 3.5330x; 1.2985x over previous
//
#include <hip/hip_runtime.h>
#include <math.h>

#define BATCH 4
#define CH 128
#define NOSC 128
#define TK 128
#define NAUD 32768
#define NVS 129          // virtual segments: 0=head, 1..127=interior k=vs-1, 128=tail

// seg tuple (8 floats, 32B): {f0h, dfh, cRev, a0, da, pad, pad, pad}
//   rev(t) = cRev + jp1*f0h + dfh*jsq ;  amp(t) = a0 + da*w ;  osc = amp*sin(2*pi*rev)

// ---------------- Stage 1: dots + phase scan -> per-segment tuples ----------------
// One block per (b,o); 256 threads = 128 knots x 2 channel-halves.
__global__ __launch_bounds__(256) void osc1_kernel(
    const float* __restrict__ x, const float* __restrict__ W,
    const float* __restrict__ bvec, const float* __restrict__ baselines,
    float* __restrict__ seg)
{
    const int blk = blockIdx.x;
    const int b = blk >> 7, o = blk & 127;
    const int tid = threadIdx.x;
    const int k = tid & 127;
    // wave-uniform channel-half base -> W reads become scalar s_loads
    const int c0 = __builtin_amdgcn_readfirstlane(tid >> 7) * 64;

    const float* __restrict__ Wr = W + (2*o)*CH;   // uniform addresses
    const float* __restrict__ Wi = Wr + CH;
    const float* xb = x + b*CH*TK + k;

    // 64 channels per thread, as two 32-deep load batches (MLP for cold misses)
    float re = 0.f, im = 0.f;
    {
        float xv[32];
        #pragma unroll
        for (int u = 0; u < 32; ++u) xv[u] = xb[(c0+u)*TK];
        #pragma unroll
        for (int u = 0; u < 32; ++u) { re = fmaf(xv[u], Wr[c0+u], re); im = fmaf(xv[u], Wi[c0+u], im); }
        #pragma unroll
        for (int u = 0; u < 32; ++u) xv[u] = xb[(c0+32+u)*TK];
        #pragma unroll
        for (int u = 0; u < 32; ++u) { re = fmaf(xv[u], Wr[c0+32+u], re); im = fmaf(xv[u], Wi[c0+32+u], im); }
    }

    __shared__ float sRe[256], sIm[256];
    sRe[tid] = re; sIm[tid] = im;
    __syncthreads();

    __shared__ float fsh[TK], ash[TK];
    __shared__ double wtot;
    float fr = 0.f, amp = 0.f;
    if (tid < 128) {
        float rr = sRe[tid] + sRe[tid+128] + bvec[2*o];
        float ii = sIm[tid] + sIm[tid+128] + bvec[2*o+1];
        rr = fmaf(rr, 0.01f, baselines[2*o]);
        ii = fmaf(ii, 0.01f, baselines[2*o+1]);
        const float BASEF  = 40.0f/11025.0f;
        const float RANGEF = 8960.0f/11025.0f;
        amp = fmaf(fmaf(rr, rr, ii*ii), RANGEF, BASEF);
        float th = atan2f(ii, rr) * (1.0f/3.14159265358979323846f);
        fr = th*th;
        fsh[k] = fr; ash[k] = amp;
    }
    __syncthreads();

    double ev = 0.0;
    if (tid < 128) {
        // segment freq-sum scan (f64), closed form per 256-sample segment
        ev = (k == 0) ? 128.0*(double)fr
                      : 128.0*((double)fsh[k-1] + (double)fr);
        const int lane = tid & 63;
        #pragma unroll
        for (int d = 1; d < 64; d <<= 1) {
            double up = __shfl_up(ev, d);
            if (lane >= d) ev += up;
        }
        if (tid == 63) wtot = ev;
    }
    __syncthreads();
    if (tid < 128) {
        if (tid >= 64) ev += wtot;
        double xrev = ev * 0.5;                    // phase base in revolutions
        float cRev = (float)(xrev - floor(xrev)); // mod 1 rev, f64 once

        float* base = seg + ((size_t)(b*NVS)*NOSC + o)*8;
        const int vs = k + 1;   // interior k<=126; tail vs=128 from k==127
        float f0h = 0.5f*fr;
        float dfh = (k <= 126) ? 0.5f*(fsh[k+1] - fr) : 0.0f;
        float da  = (k <= 126) ? (ash[k+1] - amp) : 0.0f;
        float* p = base + (size_t)vs*NOSC*8;
        *(float4*)p = make_float4(f0h, dfh, cRev, amp);
        p[4] = da;
        if (k == 0) {   // head vs=0: clamped to knot 0, phase base 0
            *(float4*)base = make_float4(f0h, 0.0f, 0.0f, amp);
            base[4] = 0.0f;
        }
    }
}

// ---------------- Stage 2: LDS-staged synthesize + in-block osc reduce ----------------
// One block per (b, 128-sample tile); 256 thr = 128 samples x 2 osc-halves of 64.
__global__ __launch_bounds__(256) void osc2_kernel(
    const float* __restrict__ seg, float* __restrict__ out)
{
    const int blk  = blockIdx.x;
    const int b    = blk >> 8;
    const int tile = blk & 255;     // == h (tile of 128 samples aligned to h)
    const int tid  = threadIdx.x;
    const int s    = tid & 127;
    const int g    = tid >> 7;

    int vs;
    if (tile == 0)        vs = 0;
    else if (tile == 255) vs = 128;
    else                  vs = ((tile - 1) >> 1) + 1;
    const int jint = s + 1 + ((tile != 0 && tile != 255 && !(tile & 1)) ? 128 : 0);
    const float jp1 = (float)jint;
    const float jsq = jp1*jp1*(1.0f/512.0f);
    const float w   = (2.0f*jp1 - 1.0f)*(1.0f/512.0f);

    // one fully-parallel coalesced shot: 256 lanes x 16B = all 128 tuples (4KB)
    __shared__ float4 tup[256];
    const float4* src = (const float4*)(seg + ((size_t)(b*NVS + vs)*NOSC)*8);
    tup[tid] = src[tid];
    __syncthreads();

    float acc = 0.0f;
    const float* base = (const float*)&tup[g*128];  // this half's 64 tuples
    #pragma unroll 8
    for (int i = 0; i < 64; ++i) {
        float4 v = *(const float4*)(base + i*8);    // broadcast ds_read_b128
        float da = base[i*8 + 4];
        float rev = fmaf(v.y, jsq, fmaf(jp1, v.x, v.z));
        float fr_;
        asm("v_fract_f32 %0, %1" : "=v"(fr_) : "v"(rev));   // rev mod 1
        float sn;
        asm("v_sin_f32 %0, %1" : "=v"(sn) : "v"(fr_));      // sin(2*pi*frac)
        acc = fmaf(fmaf(da, w, v.w), sn, acc);
    }

    __shared__ float red[256];
    red[tid] = acc;
    __syncthreads();
    if (tid < 128)
        out[b*NAUD + tile*128 + tid] = red[tid] + red[tid + 128];
}

extern "C" void kernel_launch(void* const* d_in, const int* in_sizes, int n_in,
                              void* d_out, int out_size, void* d_ws, size_t ws_size,
                              hipStream_t stream)
{
    const float* x         = (const float*)d_in[0];
    const float* W         = (const float*)d_in[1];
    const float* bvec      = (const float*)d_in[2];
    const float* baselines = (const float*)d_in[3];
    float* out = (float*)d_out;

    float* seg = (float*)d_ws;   // 4*129*128*8*4B = 2.11 MiB

    osc1_kernel<<<BATCH*NOSC, 256, 0, stream>>>(x, W, bvec, baselines, seg);
    osc2_kernel<<<BATCH*256, 256, 0, stream>>>(seg, out);
}